// Round 8
// baseline (777.180 us; speedup 1.0000x reference)
//
#include <hip/hip_runtime.h>
#include <cstdint>
#include <cstddef>

#define NY 8400
#define NR 300
#define NF 8700
#define STHR 0.5f
#define ITHR 0.5f
#define NSPLIT 8
#define NPAD 8704
#define UN 16   // gather unroll (independent loads per window)

// IOU with explicit-rounding ops so fp-contraction cannot perturb the
// iou > 0.5 comparison vs the numpy fp32 reference.
__device__ __forceinline__ float iou_pair(float4 a, float4 b) {
    float ltx = fmaxf(a.x, b.x);
    float lty = fmaxf(a.y, b.y);
    float rbx = fminf(a.z, b.z);
    float rby = fminf(a.w, b.w);
    float w = fmaxf(__fsub_rn(rbx, ltx), 0.0f);
    float h = fmaxf(__fsub_rn(rby, lty), 0.0f);
    float inter  = __fmul_rn(w, h);
    float area_a = __fmul_rn(__fsub_rn(a.z, a.x), __fsub_rn(a.w, a.y));
    float area_b = __fmul_rn(__fsub_rn(b.z, b.x), __fsub_rn(b.w, b.y));
    float denom  = __fsub_rn(__fadd_rn(area_a, area_b), inter);
    float d = denom > 0.0f ? denom : 1.0f;
    return __fdiv_rn(inter, d);
}

__global__ void prep_yolo(const float* __restrict__ y,
                          float* __restrict__ xyxy, float* __restrict__ conf, int N) {
    int i = blockIdx.x * blockDim.x + threadIdx.x;
    if (i >= N) return;
    float cx = y[0 * N + i], cy = y[1 * N + i];
    float w  = y[2 * N + i], h  = y[3 * N + i];
    float c  = y[4 * N + i];
    xyxy[i * 4 + 0] = cx - w * 0.5f;
    xyxy[i * 4 + 1] = cy - h * 0.5f;
    xyxy[i * 4 + 2] = cx + w * 0.5f;
    xyxy[i * 4 + 3] = cy + h * 0.5f;
    conf[i] = c;
}

__global__ void prep_rtdetr(const float* __restrict__ r,
                            float* __restrict__ xyxy, float* __restrict__ conf, int N) {
    __shared__ float red[512];
    int t = threadIdx.x;
    float m = -INFINITY;
    for (int i = t; i < N; i += blockDim.x) m = fmaxf(m, r[i * 5 + 4]);
    red[t] = m;
    __syncthreads();
    for (int s = 256; s > 0; s >>= 1) {
        if (t < s) red[t] = fmaxf(red[t], red[t + s]);
        __syncthreads();
    }
    float mx = red[0];
    for (int i = t; i < N; i += blockDim.x) {
        float cx = r[i * 5 + 0], cy = r[i * 5 + 1];
        float w  = r[i * 5 + 2], h  = r[i * 5 + 3];
        float c  = r[i * 5 + 4];
        xyxy[i * 4 + 0] = cx - w * 0.5f;
        xyxy[i * 4 + 1] = cy - h * 0.5f;
        xyxy[i * 4 + 2] = cx + w * 0.5f;
        xyxy[i * 4 + 3] = cy + h * 0.5f;
        conf[i] = __fdiv_rn(c, mx);
    }
}

// Partial stable-descending rank over j-slice blockIdx.y. LDS-tiled broadcast.
__global__ void rank_partial(const float* __restrict__ conf, int* __restrict__ partial, int N) {
    __shared__ float kk[1152];
    int i  = blockIdx.x * 256 + threadIdx.x;
    int js = blockIdx.y;
    int slice = (N + NSPLIT - 1) / NSPLIT;
    int j0 = js * slice;
    int j1 = min(N, j0 + slice);
    for (int j = j0 + threadIdx.x; j < j1; j += 256) {
        float c = conf[j];
        kk[j - j0] = (c >= STHR) ? c : -1.0f;
    }
    __syncthreads();
    float ci = (i < N) ? conf[i] : 0.0f;
    float ki = (ci >= STHR) ? ci : -1.0f;
    int r = 0;
    int len = j1 - j0;
    for (int jj = 0; jj < len; ++jj) {
        float kj = kk[jj];
        int j = j0 + jj;
        r += (kj > ki) || (kj == ki && j < i);
    }
    if (i < N) partial[js * NPAD + i] = r;
}

__global__ void rank_scatter(const float* __restrict__ xyxy, const float* __restrict__ conf,
                             const int* __restrict__ partial,
                             float* __restrict__ xyxy_s, float* __restrict__ conf_s, int N) {
    int i = blockIdx.x * blockDim.x + threadIdx.x;
    if (i >= N) return;
    int rank = 0;
    #pragma unroll
    for (int js = 0; js < NSPLIT; ++js) rank += partial[js * NPAD + i];
    xyxy_s[rank * 4 + 0] = xyxy[i * 4 + 0];
    xyxy_s[rank * 4 + 1] = xyxy[i * 4 + 1];
    xyxy_s[rank * 4 + 2] = xyxy[i * 4 + 2];
    xyxy_s[rank * 4 + 3] = xyxy[i * 4 + 3];
    conf_s[rank] = conf[i];
}

// TRANSPOSED mask build: maskT[c][i] = 64-bit word, bit (j-64c) set iff
// j > i && iou(i,j) > thr, for chunks c >= i>>6 (upper triangle incl. diagonal
// block). Below-diagonal never read by the gather scan -> not written.
__global__ void nms_maskT(const float* __restrict__ xyxy_s, uint64_t* __restrict__ maskT,
                          int N, int nch, int npad) {
    int i = blockIdx.x;
    int lane = threadIdx.x & 63;
    int wv   = threadIdx.x >> 6;
    float4 bi = *(const float4*)(xyxy_s + (size_t)i * 4);
    int cd = i >> 6;
    for (int c = cd + wv; c < nch; c += 4) {
        int j = (c << 6) + lane;
        bool bit = false;
        if (j < N && j > i) {
            float4 bj = *(const float4*)(xyxy_s + (size_t)j * 4);
            bit = iou_pair(bi, bj) > ITHR;
        }
        uint64_t m = __ballot(bit);
        if (lane == 0) maskT[(size_t)c * npad + i] = m;
    }
}

__device__ __forceinline__ uint64_t readlane64(uint64_t v, int k) {
    uint32_t lo = (uint32_t)__builtin_amdgcn_readlane((int)(uint32_t)v, k);
    uint32_t hi = (uint32_t)__builtin_amdgcn_readlane((int)(uint32_t)(v >> 32), k);
    return ((uint64_t)hi << 32) | lo;
}

__device__ __forceinline__ uint64_t rfl64(uint64_t v) {
    uint32_t lo = (uint32_t)__builtin_amdgcn_readfirstlane((int)(uint32_t)v);
    uint32_t hi = (uint32_t)__builtin_amdgcn_readfirstlane((int)(uint32_t)(v >> 32));
    return ((uint64_t)hi << 32) | lo;
}

__device__ __forceinline__ uint64_t shfl_xor64(uint64_t v, int m) {
    int lo = __shfl_xor((int)(uint32_t)v, m, 64);
    int hi = __shfl_xor((int)(uint32_t)(v >> 32), m, 64);
    return ((uint64_t)(uint32_t)hi << 32) | (uint32_t)lo;
}

// Single-wave gather scan. Per 64-candidate word c:
//  (1) suppression word = OR over KEPT rows r (klist, LDS) of maskT[c][r] —
//      64-lane gather, 16-deep unrolled (independent loads, one latency
//      window per 1024 kept entries), then 6-step shfl-xor OR-reduce;
//  (2) scalar greedy resolve via the diagonal block dg (double-buffered one
//      word ahead): SGPR ctz/readlane chain, no memory on the chain;
//  (3) append newly kept indices to klist via popcount-prefix (no barriers —
//      single wave). Total traffic per word: K*8 B (vs 70 KB for row-OR).
__global__ __launch_bounds__(64, 1)
void nms_scan_gather(const float* __restrict__ conf_s, const uint64_t* __restrict__ maskT,
                     uint64_t* __restrict__ removed_out, int N, int nch, int npad) {
    __shared__ int klist[NPAD];
    int lane = threadIdx.x;

    int cnt = 0;
    for (int j = lane; j < N; j += 64) cnt += (conf_s[j] >= STHR) ? 1 : 0;
    #pragma unroll
    for (int s = 32; s > 0; s >>= 1) cnt += __shfl_down(cnt, s, 64);
    int nvalid = __builtin_amdgcn_readfirstlane(__shfl(cnt, 0, 64));
    int vch = (nvalid + 63) >> 6;

    int K = 0;
    uint64_t dgA = 0, dgB = 0;
    if (vch > 0) dgA = maskT[(size_t)0 * npad + lane];   // diag block of word 0

    for (int c = 0; c < vch; ++c) {
        // prefetch next word's diagonal block (used next iteration)
        if (c + 1 < vch) dgB = maskT[(size_t)(c + 1) * npad + ((c + 1) << 6) + lane];

        const uint64_t* col = maskT + (size_t)c * npad;

        // (1) gather kept rows' column words
        uint64_t sup = 0;
        for (int j0 = 0; j0 < K; j0 += 64 * UN) {
            uint64_t t[UN];
            #pragma unroll
            for (int u = 0; u < UN; ++u) {
                int idx = j0 + (u << 6) + lane;
                int r = (idx < K) ? klist[idx] : 0;
                t[u] = (idx < K) ? col[r] : 0ull;
            }
            #pragma unroll
            for (int u = 0; u < UN; ++u) sup |= t[u];
        }
        #pragma unroll
        for (int s = 1; s < 64; s <<= 1) sup |= shfl_xor64(sup, s);

        int base = c << 6;
        uint64_t curw = rfl64(sup);
        if (base + 64 > nvalid) curw |= (~0ull) << (nvalid - base);

        // (2) scalar greedy resolve (uniform SALU chain, no memory)
        uint64_t alive = ~curw;
        uint64_t kept = 0ull;
        while (alive) {
            int k = __builtin_amdgcn_readfirstlane((int)__builtin_ctzll(alive));
            uint64_t rck = readlane64(dgA, k);
            kept |= 1ull << k;
            alive &= alive - 1;
            alive &= ~rck;
        }

        if (lane == 0) removed_out[c] = ~kept;

        // (3) append kept indices (popcount-prefix scatter into LDS)
        int mykeep = (int)((kept >> lane) & 1ull);
        int pos = K + (int)__popcll(kept & ((1ull << lane) - 1ull));
        if (mykeep) klist[pos] = base + lane;
        K += (int)__popcll(kept);

        dgA = dgB;
    }

    for (int cc = lane; cc < nch; cc += 64)
        if (cc >= vch) removed_out[cc] = ~0ull;
}

// final stage: out rows [box, conf] stride 5
__global__ void write_bs(const float* __restrict__ xyxy_s, const float* __restrict__ conf_s,
                         const uint64_t* __restrict__ removed,
                         float* __restrict__ out, int N) {
    int j = blockIdx.x * blockDim.x + threadIdx.x;
    if (j >= N) return;
    bool keep = !((removed[j >> 6] >> (j & 63)) & 1ull);
    float4 b = *(const float4*)(xyxy_s + (size_t)j * 4);
    out[j * 5 + 0] = keep ? b.x : 0.0f;
    out[j * 5 + 1] = keep ? b.y : 0.0f;
    out[j * 5 + 2] = keep ? b.z : 0.0f;
    out[j * 5 + 3] = keep ? b.w : 0.0f;
    out[j * 5 + 4] = keep ? conf_s[j] : 0.0f;
}

// stage 1/2: write kept rows straight into stage-3 input arrays (fused concat)
__global__ void write_split(const float* __restrict__ xyxy_s, const float* __restrict__ conf_s,
                            const uint64_t* __restrict__ removed,
                            float* __restrict__ xf, float* __restrict__ cf, int N, int off) {
    int j = blockIdx.x * blockDim.x + threadIdx.x;
    if (j >= N) return;
    bool keep = !((removed[j >> 6] >> (j & 63)) & 1ull);
    float4 b = *(const float4*)(xyxy_s + (size_t)j * 4);
    int o = off + j;
    xf[o * 4 + 0] = keep ? b.x : 0.0f;
    xf[o * 4 + 1] = keep ? b.y : 0.0f;
    xf[o * 4 + 2] = keep ? b.z : 0.0f;
    xf[o * 4 + 3] = keep ? b.w : 0.0f;
    cf[o] = keep ? conf_s[j] : 0.0f;
}

static void run_stage(const float* xyxy_in, const float* conf_in,
                      float* xyxy_s, float* conf_s, int* partial,
                      uint64_t* removed, uint64_t* maskT,
                      int N, hipStream_t stream,
                      float* out5, float* xf, float* cf, int off) {
    int nch = (N + 63) / 64;
    dim3 gA((N + 255) / 256, NSPLIT);
    rank_partial<<<gA, 256, 0, stream>>>(conf_in, partial, N);
    rank_scatter<<<(N + 255) / 256, 256, 0, stream>>>(xyxy_in, conf_in, partial, xyxy_s, conf_s, N);
    nms_maskT<<<N, 256, 0, stream>>>(xyxy_s, maskT, N, nch, NPAD);
    nms_scan_gather<<<1, 64, 0, stream>>>(conf_s, maskT, removed, N, nch, NPAD);
    if (out5)
        write_bs<<<(N + 255) / 256, 256, 0, stream>>>(xyxy_s, conf_s, removed, out5, N);
    else
        write_split<<<(N + 255) / 256, 256, 0, stream>>>(xyxy_s, conf_s, removed, xf, cf, N, off);
}

extern "C" void kernel_launch(void* const* d_in, const int* in_sizes, int n_in,
                              void* d_out, int out_size, void* d_ws, size_t ws_size,
                              hipStream_t stream) {
    const float* yolo   = (const float*)d_in[0];  // (1,5,8400)
    const float* rtdetr = (const float*)d_in[1];  // (1,300,5)
    float* out = (float*)d_out;                   // (8700,5)
    float* ws  = (float*)d_ws;

    // ws layout (floats)
    float* xyxy_in = ws;                 // 8700*4
    float* conf_in = ws + 34800;         // 8700
    float* xyxy_s  = ws + 43500;         // 8700*4 (16B aligned)
    float* conf_s  = ws + 78300;         // 8700
    float* xyxy_f  = ws + 87000;         // 8700*4 (stage-3 input, fused concat)
    float* conf_f  = ws + 121800;        // 8700 -> ends 130500 floats = 522000 B
    uint64_t* removed = (uint64_t*)((char*)d_ws + 522000);   // 136 u64 -> 523088
    uint64_t* maskT   = (uint64_t*)((char*)d_ws + 523088);   // <= 136*8704*8 = 9.47MB
    int* partial = (int*)maskT;          // 8*8704*4 = 278KB, dead before maskT written

    // Stage 1: YOLO
    prep_yolo<<<(NY + 255) / 256, 256, 0, stream>>>(yolo, xyxy_in, conf_in, NY);
    run_stage(xyxy_in, conf_in, xyxy_s, conf_s, partial, removed, maskT,
              NY, stream, nullptr, xyxy_f, conf_f, 0);

    // Stage 2: RT-DETR
    prep_rtdetr<<<1, 512, 0, stream>>>(rtdetr, xyxy_in, conf_in, NR);
    run_stage(xyxy_in, conf_in, xyxy_s, conf_s, partial, removed, maskT,
              NR, stream, nullptr, xyxy_f, conf_f, NY);

    // Stage 3: final over fused concat
    run_stage(xyxy_f, conf_f, xyxy_s, conf_s, partial, removed, maskT,
              NF, stream, out, nullptr, nullptr, 0);
}

// Round 9
// 436.768 us; speedup vs baseline: 1.7794x; 1.7794x over previous
//
#include <hip/hip_runtime.h>
#include <cstdint>
#include <cstddef>

#define NY 8400
#define NR 300
#define NF 8700
#define STHR 0.5f
#define ITHR 0.5f
#define NSPLIT 8
#define NPAD 8704
#define NCHMAX 136
#define WAVES 16
#define NCHPAD 137   // per-copy u64 stride (padded)

// IOU with explicit-rounding ops so fp-contraction cannot perturb the
// iou > 0.5 comparison vs the numpy fp32 reference.
__device__ __forceinline__ float iou_pair(float4 a, float4 b) {
    float ltx = fmaxf(a.x, b.x);
    float lty = fmaxf(a.y, b.y);
    float rbx = fminf(a.z, b.z);
    float rby = fminf(a.w, b.w);
    float w = fmaxf(__fsub_rn(rbx, ltx), 0.0f);
    float h = fmaxf(__fsub_rn(rby, lty), 0.0f);
    float inter  = __fmul_rn(w, h);
    float area_a = __fmul_rn(__fsub_rn(a.z, a.x), __fsub_rn(a.w, a.y));
    float area_b = __fmul_rn(__fsub_rn(b.z, b.x), __fsub_rn(b.w, b.y));
    float denom  = __fsub_rn(__fadd_rn(area_a, area_b), inter);
    float d = denom > 0.0f ? denom : 1.0f;
    return __fdiv_rn(inter, d);
}

__global__ void prep_yolo(const float* __restrict__ y,
                          float* __restrict__ xyxy, float* __restrict__ conf, int N) {
    int i = blockIdx.x * blockDim.x + threadIdx.x;
    if (i >= N) return;
    float cx = y[0 * N + i], cy = y[1 * N + i];
    float w  = y[2 * N + i], h  = y[3 * N + i];
    float c  = y[4 * N + i];
    xyxy[i * 4 + 0] = cx - w * 0.5f;
    xyxy[i * 4 + 1] = cy - h * 0.5f;
    xyxy[i * 4 + 2] = cx + w * 0.5f;
    xyxy[i * 4 + 3] = cy + h * 0.5f;
    conf[i] = c;
}

__global__ void prep_rtdetr(const float* __restrict__ r,
                            float* __restrict__ xyxy, float* __restrict__ conf, int N) {
    __shared__ float red[512];
    int t = threadIdx.x;
    float m = -INFINITY;
    for (int i = t; i < N; i += blockDim.x) m = fmaxf(m, r[i * 5 + 4]);
    red[t] = m;
    __syncthreads();
    for (int s = 256; s > 0; s >>= 1) {
        if (t < s) red[t] = fmaxf(red[t], red[t + s]);
        __syncthreads();
    }
    float mx = red[0];
    for (int i = t; i < N; i += blockDim.x) {
        float cx = r[i * 5 + 0], cy = r[i * 5 + 1];
        float w  = r[i * 5 + 2], h  = r[i * 5 + 3];
        float c  = r[i * 5 + 4];
        xyxy[i * 4 + 0] = cx - w * 0.5f;
        xyxy[i * 4 + 1] = cy - h * 0.5f;
        xyxy[i * 4 + 2] = cx + w * 0.5f;
        xyxy[i * 4 + 3] = cy + h * 0.5f;
        conf[i] = __fdiv_rn(c, mx);
    }
}

// Partial stable-descending rank over j-slice blockIdx.y. LDS-tiled broadcast.
__global__ void rank_partial(const float* __restrict__ conf, int* __restrict__ partial, int N) {
    __shared__ float kk[1152];
    int i  = blockIdx.x * 256 + threadIdx.x;
    int js = blockIdx.y;
    int slice = (N + NSPLIT - 1) / NSPLIT;
    int j0 = js * slice;
    int j1 = min(N, j0 + slice);
    for (int j = j0 + threadIdx.x; j < j1; j += 256) {
        float c = conf[j];
        kk[j - j0] = (c >= STHR) ? c : -1.0f;
    }
    __syncthreads();
    float ci = (i < N) ? conf[i] : 0.0f;
    float ki = (ci >= STHR) ? ci : -1.0f;
    int r = 0;
    int len = j1 - j0;
    for (int jj = 0; jj < len; ++jj) {
        float kj = kk[jj];
        int j = j0 + jj;
        r += (kj > ki) || (kj == ki && j < i);
    }
    if (i < N) partial[js * NPAD + i] = r;
}

__global__ void rank_scatter(const float* __restrict__ xyxy, const float* __restrict__ conf,
                             const int* __restrict__ partial,
                             float* __restrict__ xyxy_s, float* __restrict__ conf_s, int N) {
    int i = blockIdx.x * blockDim.x + threadIdx.x;
    if (i >= N) return;
    int rank = 0;
    #pragma unroll
    for (int js = 0; js < NSPLIT; ++js) rank += partial[js * NPAD + i];
    xyxy_s[rank * 4 + 0] = xyxy[i * 4 + 0];
    xyxy_s[rank * 4 + 1] = xyxy[i * 4 + 1];
    xyxy_s[rank * 4 + 2] = xyxy[i * 4 + 2];
    xyxy_s[rank * 4 + 3] = xyxy[i * 4 + 3];
    conf_s[rank] = conf[i];
}

// One block per row i; 4 waves stride chunks. Below-diagonal chunks zero-filled.
// Also writes diag[i] = mask[i][i>>6] (the 64x64 diagonal block words).
__global__ void nms_mask_row(const float* __restrict__ xyxy_s, uint64_t* __restrict__ mask,
                             uint64_t* __restrict__ diag, int N, int nch, int stride) {
    int i = blockIdx.x;
    int lane = threadIdx.x & 63;
    int wv   = threadIdx.x >> 6;
    float4 bi = *(const float4*)(xyxy_s + (size_t)i * 4);
    int cd = i >> 6;
    for (int c = wv; c < nch; c += 4) {
        if (c < cd) {
            if (lane == 0) mask[(size_t)i * stride + c] = 0ull;
            continue;
        }
        int j = (c << 6) + lane;
        bool bit = false;
        if (j < N && j > i) {
            float4 bj = *(const float4*)(xyxy_s + (size_t)j * 4);
            bit = iou_pair(bi, bj) > ITHR;
        }
        uint64_t m = __ballot(bit);
        if (lane == 0) {
            mask[(size_t)i * stride + c] = m;
            if (c == cd) diag[i] = m;
        }
    }
}

__device__ __forceinline__ uint64_t readlane64(uint64_t v, int k) {
    uint32_t lo = (uint32_t)__builtin_amdgcn_readlane((int)(uint32_t)v, k);
    uint32_t hi = (uint32_t)__builtin_amdgcn_readlane((int)(uint32_t)(v >> 32), k);
    return ((uint64_t)hi << 32) | lo;
}

__device__ __forceinline__ uint64_t rfl64(uint64_t v) {
    uint32_t lo = (uint32_t)__builtin_amdgcn_readfirstlane((int)(uint32_t)v);
    uint32_t hi = (uint32_t)__builtin_amdgcn_readfirstlane((int)(uint32_t)(v >> 32));
    return ((uint64_t)hi << 32) | lo;
}

// Multi-wave scan v3 (round-7 structure + SPARSE resolve + fused epilogue).
// Per 64-candidate word c:  bar -> ISSUE next word's rows (speculative, TLP,
// coalesced) -> wave 0 resolves kept-set:
//   alive = ~(OR of 16 LDS copies' word c | tail),
//   S = ballot(dg & alive) & alive   (lanes that can suppress something alive)
//   serial chain over S ONLY (~4 iters on this data, vs 60 for all-alive)
// -> bar -> all waves OR their kept rows into their own LDS copy (branchless).
// Epilogue: write [box,conf]/0 rows directly (no removed buffer, no extra kernel).
__global__ __launch_bounds__(1024, 1)
void nms_scan_mw(const float* __restrict__ conf_s, const uint64_t* __restrict__ mask,
                 const uint64_t* __restrict__ diag, const float* __restrict__ xyxy_s,
                 float* __restrict__ out5, float* __restrict__ xf, float* __restrict__ cf,
                 int off, int N, int nch, int stride) {
    __shared__ uint64_t bmflat[WAVES * NCHPAD];
    __shared__ uint64_t keptw[NCHMAX];
    __shared__ int redcnt[WAVES];

    int tid  = threadIdx.x;
    int wv   = tid >> 6;
    int lane = tid & 63;
    bool hastail = (128 + lane) < nch;

    // zero copies + count valid, one barrier
    for (int idx = tid; idx < WAVES * NCHPAD; idx += 1024) bmflat[idx] = 0ull;
    int cnt = 0;
    for (int j = tid; j < N; j += 1024) cnt += (conf_s[j] >= STHR) ? 1 : 0;
    #pragma unroll
    for (int s = 32; s > 0; s >>= 1) cnt += __shfl_down(cnt, s, 64);
    if (lane == 0) redcnt[wv] = cnt;
    __syncthreads();
    int nvalid = 0;
    #pragma unroll
    for (int q = 0; q < WAVES; ++q) nvalid += redcnt[q];

    int vch = (nvalid + 63) >> 6;

    ulonglong2 sA[4], sB[4];
    uint64_t tA[4] = {0,0,0,0}, tB[4] = {0,0,0,0};
    uint64_t dgA = 0, dgB = 0;
    #pragma unroll
    for (int q = 0; q < 4; ++q) { sA[q].x = sA[q].y = 0ull; sB[q].x = sB[q].y = 0ull; }

#define ISSUE(S, CW) do {                                                     \
    int _c = (CW);                                                            \
    if (_c < vch) {                                                           \
        int base = _c << 6;                                                   \
        dg##S = diag[base + lane];                                            \
        _Pragma("unroll")                                                     \
        for (int q = 0; q < 4; ++q) {                                         \
            int row = base + (wv << 2) + q;                                   \
            row = row < N ? row : N - 1;                                      \
            const uint64_t* rb = mask + (size_t)row * stride;                 \
            s##S[q] = *((const ulonglong2*)rb + lane);                        \
            t##S[q] = hastail ? rb[128 + lane] : 0ull;                        \
        }                                                                     \
    }                                                                         \
} while (0)

// wave 0 only: sparse greedy resolve of word CW. Only lanes whose diag word
// intersects `alive` (set S) need serial processing; everyone else's keep
// status is alive & ~sup. Exact: any in-word suppressor of an alive box is
// in S by construction.
#define RESOLVE(S, CW) do {                                                   \
    int _c = (CW);                                                            \
    if (_c < vch && wv == 0) {                                                \
        int base = _c << 6;                                                   \
        uint64_t curw_v = (base + 64 > nvalid)                                \
            ? ((nvalid > base) ? (~0ull << (nvalid - base)) : ~0ull) : 0ull;  \
        _Pragma("unroll")                                                     \
        for (int q = 0; q < WAVES; ++q) curw_v |= bmflat[q * NCHPAD + _c];    \
        uint64_t alive = ~rfl64(curw_v);                                      \
        uint64_t Sset = __ballot((dg##S & alive) != 0ull) & alive;            \
        uint64_t sup = 0ull;                                                  \
        while (Sset) {                                                        \
            int k = __builtin_amdgcn_readfirstlane((int)__builtin_ctzll(Sset)); \
            uint64_t rck = readlane64(dg##S, k);                              \
            if (!((sup >> k) & 1ull)) sup |= rck;                             \
            Sset &= Sset - 1;                                                 \
            Sset &= ~sup;                                                     \
        }                                                                     \
        uint64_t kept = alive & ~sup;                                         \
        if (lane == 0) keptw[_c] = kept;                                      \
    }                                                                         \
} while (0)

#define ORPH(S, CW) do {                                                      \
    int _c = (CW);                                                            \
    if (_c < vch) {                                                           \
        uint64_t kept = keptw[_c];                                            \
        uint64_t a0 = 0, a1 = 0, at = 0;                                      \
        _Pragma("unroll")                                                     \
        for (int q = 0; q < 4; ++q) {                                         \
            uint64_t mk = 0ull - ((kept >> ((wv << 2) + q)) & 1ull);          \
            a0 |= s##S[q].x & mk; a1 |= s##S[q].y & mk; at |= t##S[q] & mk;   \
        }                                                                     \
        bmflat[wv * NCHPAD + 2 * lane]     |= a0;                             \
        bmflat[wv * NCHPAD + 2 * lane + 1] |= a1;                             \
        if (hastail) bmflat[wv * NCHPAD + 128 + lane] |= at;                  \
    }                                                                         \
} while (0)

    ISSUE(A, 0);
    for (int c = 0; c < vch; c += 2) {
        __syncthreads();          // prev word's ORs visible
        ISSUE(B, c + 1);          // speculative, drains under resolve at next bar
        RESOLVE(A, c);
        __syncthreads();          // keptw visible; resolver done reading copies
        ORPH(A, c);
        __syncthreads();
        ISSUE(A, c + 2);
        RESOLVE(B, c + 1);
        __syncthreads();
        ORPH(B, c + 1);
    }
#undef ISSUE
#undef RESOLVE
#undef ORPH

    __syncthreads();
    // fused epilogue: write rows (kept ? [box,conf] : 0)
    for (int j = tid; j < N; j += 1024) {
        int w = j >> 6;
        uint64_t kw = (w < vch) ? keptw[w] : 0ull;
        bool keep = (kw >> (j & 63)) & 1ull;
        float4 b = *(const float4*)(xyxy_s + (size_t)j * 4);
        float cv = conf_s[j];
        if (out5) {
            out5[j * 5 + 0] = keep ? b.x : 0.0f;
            out5[j * 5 + 1] = keep ? b.y : 0.0f;
            out5[j * 5 + 2] = keep ? b.z : 0.0f;
            out5[j * 5 + 3] = keep ? b.w : 0.0f;
            out5[j * 5 + 4] = keep ? cv  : 0.0f;
        } else {
            int o = off + j;
            xf[o * 4 + 0] = keep ? b.x : 0.0f;
            xf[o * 4 + 1] = keep ? b.y : 0.0f;
            xf[o * 4 + 2] = keep ? b.z : 0.0f;
            xf[o * 4 + 3] = keep ? b.w : 0.0f;
            cf[o] = keep ? cv : 0.0f;
        }
    }
}

static void run_stage(const float* xyxy_in, const float* conf_in,
                      float* xyxy_s, float* conf_s, int* partial,
                      uint64_t* mask, uint64_t* diag,
                      int N, int stride, hipStream_t stream,
                      float* out5, float* xf, float* cf, int off) {
    int nch = (N + 63) / 64;
    dim3 gA((N + 255) / 256, NSPLIT);
    rank_partial<<<gA, 256, 0, stream>>>(conf_in, partial, N);
    rank_scatter<<<(N + 255) / 256, 256, 0, stream>>>(xyxy_in, conf_in, partial, xyxy_s, conf_s, N);
    nms_mask_row<<<N, 256, 0, stream>>>(xyxy_s, mask, diag, N, nch, stride);
    nms_scan_mw<<<1, 1024, 0, stream>>>(conf_s, mask, diag, xyxy_s,
                                        out5, xf, cf, off, N, nch, stride);
}

extern "C" void kernel_launch(void* const* d_in, const int* in_sizes, int n_in,
                              void* d_out, int out_size, void* d_ws, size_t ws_size,
                              hipStream_t stream) {
    const float* yolo   = (const float*)d_in[0];  // (1,5,8400)
    const float* rtdetr = (const float*)d_in[1];  // (1,300,5)
    float* out = (float*)d_out;                   // (8700,5)
    float* ws  = (float*)d_ws;

    // ws layout (floats) — identical to the validated round-7 layout
    float* xyxy_in = ws;                 // 8700*4 = 139200 B
    float* conf_in = ws + 34800;         // 8700
    float* xyxy_s  = ws + 43500;         // 8700*4 (16B aligned)
    float* conf_s  = ws + 78300;         // 8700
    float* xyxy_f  = ws + 87000;         // 8700*4 (stage-3 input, fused concat)
    float* conf_f  = ws + 121800;        // 8700 -> ends 130500 floats = 522000 B
    uint64_t* mask = (uint64_t*)((char*)d_ws + 523088);   // <= 8700*136*8 B
    int* partial = (int*)mask;           // 8*8704*4 = 278KB, dead before mask written
    // diag (NPAD u64) aliases xyxy_in: last read of xyxy_in is rank_scatter;
    // diag written by nms_mask_row (later), read by the scan; next stage's
    // prep rewrites xyxy_in after the scan completes.
    uint64_t* diag = (uint64_t*)d_ws;

    // Stage 1: YOLO (stride = nch = 132)
    prep_yolo<<<(NY + 255) / 256, 256, 0, stream>>>(yolo, xyxy_in, conf_in, NY);
    run_stage(xyxy_in, conf_in, xyxy_s, conf_s, partial, mask, diag,
              NY, 132, stream, nullptr, xyxy_f, conf_f, 0);

    // Stage 2: RT-DETR (nch = 5, stride padded to 6)
    prep_rtdetr<<<1, 512, 0, stream>>>(rtdetr, xyxy_in, conf_in, NR);
    run_stage(xyxy_in, conf_in, xyxy_s, conf_s, partial, mask, diag,
              NR, 6, stream, nullptr, xyxy_f, conf_f, NY);

    // Stage 3: final over fused concat (stride = nch = 136)
    run_stage(xyxy_f, conf_f, xyxy_s, conf_s, partial, mask, diag,
              NF, 136, stream, out, nullptr, nullptr, 0);
}

// Round 10
// 393.116 us; speedup vs baseline: 1.9770x; 1.1110x over previous
//
#include <hip/hip_runtime.h>
#include <cstdint>
#include <cstddef>

#define NY 8400
#define NR 300
#define NF 8700
#define STHR 0.5f
#define ITHR 0.5f
#define NSPLIT 8
#define NPAD 8704
#define NCHMAX 136
#define WAVES 16
#define NCHPAD 137   // per-copy u64 stride (padded)

// IOU with explicit-rounding ops so fp-contraction cannot perturb the
// iou > 0.5 comparison vs the numpy fp32 reference.
__device__ __forceinline__ float iou_pair(float4 a, float4 b) {
    float ltx = fmaxf(a.x, b.x);
    float lty = fmaxf(a.y, b.y);
    float rbx = fminf(a.z, b.z);
    float rby = fminf(a.w, b.w);
    float w = fmaxf(__fsub_rn(rbx, ltx), 0.0f);
    float h = fmaxf(__fsub_rn(rby, lty), 0.0f);
    float inter  = __fmul_rn(w, h);
    float area_a = __fmul_rn(__fsub_rn(a.z, a.x), __fsub_rn(a.w, a.y));
    float area_b = __fmul_rn(__fsub_rn(b.z, b.x), __fsub_rn(b.w, b.y));
    float denom  = __fsub_rn(__fadd_rn(area_a, area_b), inter);
    float d = denom > 0.0f ? denom : 1.0f;
    return __fdiv_rn(inter, d);
}

__global__ void prep_yolo(const float* __restrict__ y,
                          float* __restrict__ xyxy, float* __restrict__ conf, int N) {
    int i = blockIdx.x * blockDim.x + threadIdx.x;
    if (i >= N) return;
    float cx = y[0 * N + i], cy = y[1 * N + i];
    float w  = y[2 * N + i], h  = y[3 * N + i];
    float c  = y[4 * N + i];
    xyxy[i * 4 + 0] = cx - w * 0.5f;
    xyxy[i * 4 + 1] = cy - h * 0.5f;
    xyxy[i * 4 + 2] = cx + w * 0.5f;
    xyxy[i * 4 + 3] = cy + h * 0.5f;
    conf[i] = c;
}

__global__ void prep_rtdetr(const float* __restrict__ r,
                            float* __restrict__ xyxy, float* __restrict__ conf, int N) {
    __shared__ float red[512];
    int t = threadIdx.x;
    float m = -INFINITY;
    for (int i = t; i < N; i += blockDim.x) m = fmaxf(m, r[i * 5 + 4]);
    red[t] = m;
    __syncthreads();
    for (int s = 256; s > 0; s >>= 1) {
        if (t < s) red[t] = fmaxf(red[t], red[t + s]);
        __syncthreads();
    }
    float mx = red[0];
    for (int i = t; i < N; i += blockDim.x) {
        float cx = r[i * 5 + 0], cy = r[i * 5 + 1];
        float w  = r[i * 5 + 2], h  = r[i * 5 + 3];
        float c  = r[i * 5 + 4];
        xyxy[i * 4 + 0] = cx - w * 0.5f;
        xyxy[i * 4 + 1] = cy - h * 0.5f;
        xyxy[i * 4 + 2] = cx + w * 0.5f;
        xyxy[i * 4 + 3] = cy + h * 0.5f;
        conf[i] = __fdiv_rn(c, mx);
    }
}

// Partial stable-descending rank over j-slice blockIdx.y. LDS-tiled broadcast.
__global__ void rank_partial(const float* __restrict__ conf, int* __restrict__ partial, int N) {
    __shared__ float kk[1152];
    int i  = blockIdx.x * 256 + threadIdx.x;
    int js = blockIdx.y;
    int slice = (N + NSPLIT - 1) / NSPLIT;
    int j0 = js * slice;
    int j1 = min(N, j0 + slice);
    for (int j = j0 + threadIdx.x; j < j1; j += 256) {
        float c = conf[j];
        kk[j - j0] = (c >= STHR) ? c : -1.0f;
    }
    __syncthreads();
    float ci = (i < N) ? conf[i] : 0.0f;
    float ki = (ci >= STHR) ? ci : -1.0f;
    int r = 0;
    int len = j1 - j0;
    for (int jj = 0; jj < len; ++jj) {
        float kj = kk[jj];
        int j = j0 + jj;
        r += (kj > ki) || (kj == ki && j < i);
    }
    if (i < N) partial[js * NPAD + i] = r;
}

__global__ void rank_scatter(const float* __restrict__ xyxy, const float* __restrict__ conf,
                             const int* __restrict__ partial,
                             float* __restrict__ xyxy_s, float* __restrict__ conf_s, int N) {
    int i = blockIdx.x * blockDim.x + threadIdx.x;
    if (i >= N) return;
    int rank = 0;
    #pragma unroll
    for (int js = 0; js < NSPLIT; ++js) rank += partial[js * NPAD + i];
    xyxy_s[rank * 4 + 0] = xyxy[i * 4 + 0];
    xyxy_s[rank * 4 + 1] = xyxy[i * 4 + 1];
    xyxy_s[rank * 4 + 2] = xyxy[i * 4 + 2];
    xyxy_s[rank * 4 + 3] = xyxy[i * 4 + 3];
    conf_s[rank] = conf[i];
}

// One block per row i; 4 waves stride chunks. Below-diagonal chunks zero-filled.
// Also writes diag[i] = mask[i][i>>6] (the 64x64 diagonal block words).
__global__ void nms_mask_row(const float* __restrict__ xyxy_s, uint64_t* __restrict__ mask,
                             uint64_t* __restrict__ diag, int N, int nch, int stride) {
    int i = blockIdx.x;
    int lane = threadIdx.x & 63;
    int wv   = threadIdx.x >> 6;
    float4 bi = *(const float4*)(xyxy_s + (size_t)i * 4);
    int cd = i >> 6;
    for (int c = wv; c < nch; c += 4) {
        if (c < cd) {
            if (lane == 0) mask[(size_t)i * stride + c] = 0ull;
            continue;
        }
        int j = (c << 6) + lane;
        bool bit = false;
        if (j < N && j > i) {
            float4 bj = *(const float4*)(xyxy_s + (size_t)j * 4);
            bit = iou_pair(bi, bj) > ITHR;
        }
        uint64_t m = __ballot(bit);
        if (lane == 0) {
            mask[(size_t)i * stride + c] = m;
            if (c == cd) diag[i] = m;
        }
    }
}

__device__ __forceinline__ uint64_t readlane64(uint64_t v, int k) {
    uint32_t lo = (uint32_t)__builtin_amdgcn_readlane((int)(uint32_t)v, k);
    uint32_t hi = (uint32_t)__builtin_amdgcn_readlane((int)(uint32_t)(v >> 32), k);
    return ((uint64_t)hi << 32) | lo;
}

__device__ __forceinline__ uint64_t rfl64(uint64_t v) {
    uint32_t lo = (uint32_t)__builtin_amdgcn_readfirstlane((int)(uint32_t)v);
    uint32_t hi = (uint32_t)__builtin_amdgcn_readfirstlane((int)(uint32_t)(v >> 32));
    return ((uint64_t)hi << 32) | lo;
}

// Multi-wave scan v4 = round-9 validated structure + TRIANGULAR LOAD PRUNING.
// Rows of word c only have nonzero chunks in [c, nch) (below-diagonal is
// zero-filled), and chunks >= vch only affect bitmap words the scan never
// resolves (invalid candidates). So ISSUE loads only chunks in [c, vch):
// pair-lane active iff 2l+1 >= c && 2l < vch; row active iff row < nvalid.
// Skipped lanes contribute zeros -> ORPH/RESOLVE semantics unchanged.
// ~4x less single-CU L2-fill traffic per word.
__global__ __launch_bounds__(1024, 1)
void nms_scan_mw(const float* __restrict__ conf_s, const uint64_t* __restrict__ mask,
                 const uint64_t* __restrict__ diag, const float* __restrict__ xyxy_s,
                 float* __restrict__ out5, float* __restrict__ xf, float* __restrict__ cf,
                 int off, int N, int nch, int stride) {
    __shared__ uint64_t bmflat[WAVES * NCHPAD];
    __shared__ uint64_t keptw[NCHMAX];
    __shared__ int redcnt[WAVES];

    int tid  = threadIdx.x;
    int wv   = tid >> 6;
    int lane = tid & 63;
    bool hastail = (128 + lane) < nch;

    // zero copies + count valid, one barrier
    for (int idx = tid; idx < WAVES * NCHPAD; idx += 1024) bmflat[idx] = 0ull;
    int cnt = 0;
    for (int j = tid; j < N; j += 1024) cnt += (conf_s[j] >= STHR) ? 1 : 0;
    #pragma unroll
    for (int s = 32; s > 0; s >>= 1) cnt += __shfl_down(cnt, s, 64);
    if (lane == 0) redcnt[wv] = cnt;
    __syncthreads();
    int nvalid = 0;
    #pragma unroll
    for (int q = 0; q < WAVES; ++q) nvalid += redcnt[q];

    int vch = (nvalid + 63) >> 6;

    ulonglong2 sA[4], sB[4];
    uint64_t tA[4] = {0,0,0,0}, tB[4] = {0,0,0,0};
    uint64_t dgA = 0, dgB = 0;
    #pragma unroll
    for (int q = 0; q < 4; ++q) { sA[q].x = sA[q].y = 0ull; sB[q].x = sB[q].y = 0ull; }

#define ISSUE(S, CW) do {                                                     \
    int _c = (CW);                                                            \
    if (_c < vch) {                                                           \
        int base = _c << 6;                                                   \
        dg##S = diag[base + lane];                                            \
        bool pairok = (2 * lane + 1 >= _c) && (2 * lane < vch);               \
        bool tailok = hastail && (128 + lane >= _c) && (128 + lane < vch);    \
        _Pragma("unroll")                                                     \
        for (int q = 0; q < 4; ++q) {                                         \
            int row = base + (wv << 2) + q;                                   \
            bool rok = row < nvalid;                                          \
            row = row < N ? row : N - 1;                                      \
            const uint64_t* rb = mask + (size_t)row * stride;                 \
            ulonglong2 v; v.x = 0ull; v.y = 0ull;                             \
            if (pairok && rok) v = *((const ulonglong2*)rb + lane);           \
            s##S[q] = v;                                                      \
            t##S[q] = (tailok && rok) ? rb[128 + lane] : 0ull;                \
        }                                                                     \
    }                                                                         \
} while (0)

// wave 0 only: sparse greedy resolve of word CW. Only lanes whose diag word
// intersects `alive` (set S) need serial processing; everyone else's keep
// status is alive & ~sup. Exact: any in-word suppressor of an alive box is
// in S by construction.
#define RESOLVE(S, CW) do {                                                   \
    int _c = (CW);                                                            \
    if (_c < vch && wv == 0) {                                                \
        int base = _c << 6;                                                   \
        uint64_t curw_v = (base + 64 > nvalid)                                \
            ? ((nvalid > base) ? (~0ull << (nvalid - base)) : ~0ull) : 0ull;  \
        _Pragma("unroll")                                                     \
        for (int q = 0; q < WAVES; ++q) curw_v |= bmflat[q * NCHPAD + _c];    \
        uint64_t alive = ~rfl64(curw_v);                                      \
        uint64_t Sset = __ballot((dg##S & alive) != 0ull) & alive;            \
        uint64_t sup = 0ull;                                                  \
        while (Sset) {                                                        \
            int k = __builtin_amdgcn_readfirstlane((int)__builtin_ctzll(Sset)); \
            uint64_t rck = readlane64(dg##S, k);                              \
            if (!((sup >> k) & 1ull)) sup |= rck;                             \
            Sset &= Sset - 1;                                                 \
            Sset &= ~sup;                                                     \
        }                                                                     \
        uint64_t kept = alive & ~sup;                                         \
        if (lane == 0) keptw[_c] = kept;                                      \
    }                                                                         \
} while (0)

#define ORPH(S, CW) do {                                                      \
    int _c = (CW);                                                            \
    if (_c < vch) {                                                           \
        uint64_t kept = keptw[_c];                                            \
        uint64_t a0 = 0, a1 = 0, at = 0;                                      \
        _Pragma("unroll")                                                     \
        for (int q = 0; q < 4; ++q) {                                         \
            uint64_t mk = 0ull - ((kept >> ((wv << 2) + q)) & 1ull);          \
            a0 |= s##S[q].x & mk; a1 |= s##S[q].y & mk; at |= t##S[q] & mk;   \
        }                                                                     \
        bmflat[wv * NCHPAD + 2 * lane]     |= a0;                             \
        bmflat[wv * NCHPAD + 2 * lane + 1] |= a1;                             \
        if (hastail) bmflat[wv * NCHPAD + 128 + lane] |= at;                  \
    }                                                                         \
} while (0)

    ISSUE(A, 0);
    for (int c = 0; c < vch; c += 2) {
        __syncthreads();          // prev word's ORs visible
        ISSUE(B, c + 1);          // speculative, drains under resolve at next bar
        RESOLVE(A, c);
        __syncthreads();          // keptw visible; resolver done reading copies
        ORPH(A, c);
        __syncthreads();
        ISSUE(A, c + 2);
        RESOLVE(B, c + 1);
        __syncthreads();
        ORPH(B, c + 1);
    }
#undef ISSUE
#undef RESOLVE
#undef ORPH

    __syncthreads();
    // fused epilogue: write rows (kept ? [box,conf] : 0)
    for (int j = tid; j < N; j += 1024) {
        int w = j >> 6;
        uint64_t kw = (w < vch) ? keptw[w] : 0ull;
        bool keep = (kw >> (j & 63)) & 1ull;
        float4 b = *(const float4*)(xyxy_s + (size_t)j * 4);
        float cv = conf_s[j];
        if (out5) {
            out5[j * 5 + 0] = keep ? b.x : 0.0f;
            out5[j * 5 + 1] = keep ? b.y : 0.0f;
            out5[j * 5 + 2] = keep ? b.z : 0.0f;
            out5[j * 5 + 3] = keep ? b.w : 0.0f;
            out5[j * 5 + 4] = keep ? cv  : 0.0f;
        } else {
            int o = off + j;
            xf[o * 4 + 0] = keep ? b.x : 0.0f;
            xf[o * 4 + 1] = keep ? b.y : 0.0f;
            xf[o * 4 + 2] = keep ? b.z : 0.0f;
            xf[o * 4 + 3] = keep ? b.w : 0.0f;
            cf[o] = keep ? cv : 0.0f;
        }
    }
}

static void run_stage(const float* xyxy_in, const float* conf_in,
                      float* xyxy_s, float* conf_s, int* partial,
                      uint64_t* mask, uint64_t* diag,
                      int N, int stride, hipStream_t stream,
                      float* out5, float* xf, float* cf, int off) {
    int nch = (N + 63) / 64;
    dim3 gA((N + 255) / 256, NSPLIT);
    rank_partial<<<gA, 256, 0, stream>>>(conf_in, partial, N);
    rank_scatter<<<(N + 255) / 256, 256, 0, stream>>>(xyxy_in, conf_in, partial, xyxy_s, conf_s, N);
    nms_mask_row<<<N, 256, 0, stream>>>(xyxy_s, mask, diag, N, nch, stride);
    nms_scan_mw<<<1, 1024, 0, stream>>>(conf_s, mask, diag, xyxy_s,
                                        out5, xf, cf, off, N, nch, stride);
}

extern "C" void kernel_launch(void* const* d_in, const int* in_sizes, int n_in,
                              void* d_out, int out_size, void* d_ws, size_t ws_size,
                              hipStream_t stream) {
    const float* yolo   = (const float*)d_in[0];  // (1,5,8400)
    const float* rtdetr = (const float*)d_in[1];  // (1,300,5)
    float* out = (float*)d_out;                   // (8700,5)
    float* ws  = (float*)d_ws;

    // ws layout (floats) — identical to the validated round-9 layout
    float* xyxy_in = ws;                 // 8700*4 = 139200 B
    float* conf_in = ws + 34800;         // 8700
    float* xyxy_s  = ws + 43500;         // 8700*4 (16B aligned)
    float* conf_s  = ws + 78300;         // 8700
    float* xyxy_f  = ws + 87000;         // 8700*4 (stage-3 input, fused concat)
    float* conf_f  = ws + 121800;        // 8700 -> ends 130500 floats = 522000 B
    uint64_t* mask = (uint64_t*)((char*)d_ws + 523088);   // <= 8700*136*8 B
    int* partial = (int*)mask;           // 8*8704*4 = 278KB, dead before mask written
    // diag (NPAD u64) aliases xyxy_in: last read of xyxy_in is rank_scatter;
    // diag written by nms_mask_row (later), read by the scan; next stage's
    // prep rewrites xyxy_in after the scan completes.
    uint64_t* diag = (uint64_t*)d_ws;

    // Stage 1: YOLO (stride = nch = 132)
    prep_yolo<<<(NY + 255) / 256, 256, 0, stream>>>(yolo, xyxy_in, conf_in, NY);
    run_stage(xyxy_in, conf_in, xyxy_s, conf_s, partial, mask, diag,
              NY, 132, stream, nullptr, xyxy_f, conf_f, 0);

    // Stage 2: RT-DETR (nch = 5, stride padded to 6)
    prep_rtdetr<<<1, 512, 0, stream>>>(rtdetr, xyxy_in, conf_in, NR);
    run_stage(xyxy_in, conf_in, xyxy_s, conf_s, partial, mask, diag,
              NR, 6, stream, nullptr, xyxy_f, conf_f, NY);

    // Stage 3: final over fused concat (stride = nch = 136)
    run_stage(xyxy_f, conf_f, xyxy_s, conf_s, partial, mask, diag,
              NF, 136, stream, out, nullptr, nullptr, 0);
}